// Round 10
// baseline (506.010 us; speedup 1.0000x reference)
//
#include <hip/hip_runtime.h>

// Problem constants
#define NVEC 65536      // B*R*C = 8*16*512
#define KDIM 64
#define SDIM 512

// Output layout (flat float32)
#define Z_OFF       4194304     // NVEC*KDIM
#define LCOMMIT_OFF 4259840
#define LCODE_OFF   4259841
#define E_OFF       4259842

typedef _Float16 half8    __attribute__((ext_vector_type(8)));
typedef float    floatx16 __attribute__((ext_vector_type(16)));

// ws layout (floats): c32 [32768], cnorm [512], cbf16 [65536 halfs], partial [2048]
// cbf16 chunk layout (R4-verified): half index
//   (s>>5)*4096 + p*2048 + q*512 + h*256 + (s&31)*8 + j
// -> per-lane read: bb = cbf16 + j*4096 + lane*8, bh at +q*512, bl at +2048+q*512.

__global__ void vq_prep(const float* __restrict__ c_sum,
                        const float* __restrict__ c_count,
                        float* __restrict__ c32,
                        float* __restrict__ cnorm,
                        _Float16* __restrict__ cbf16) {
    int s = blockIdx.x;          // 0..511
    int k = threadIdx.x;         // 0..63
    float cnt = c_count[s];
    float inv = 1.0f / fmaxf(cnt, 0.01f);
    float x = c_sum[s * KDIM + k] * inv;
    c32[s * KDIM + k] = x;
    float sq = x * x;
    #pragma unroll
    for (int off = 32; off > 0; off >>= 1)
        sq += __shfl_down(sq, off);
    if (k == 0) cnorm[s] = sq;

    __shared__ _Float16 hb[64], lb[64];
    _Float16 hi = (_Float16)x;
    float hiF = (float)hi;
    _Float16 lo = (_Float16)(x - hiF);
    hb[k] = hi; lb[k] = lo;
    __syncthreads();
    if (k < 16) {
        int p  = k >> 3;
        int qh = k & 7;                       // q*2 + h
        int k0 = (qh >> 1) * 16 + (qh & 1) * 8;
        const _Float16* srcb = (p ? lb : hb) + k0;
        half8 v;
        #pragma unroll
        for (int j = 0; j < 8; ++j) v[j] = srcb[j];
        size_t chunk = ((size_t)(s >> 5) * 16 + p * 8 + qh) * 32 + (s & 31);
        *(half8*)(cbf16 + chunk * 8) = v;
    }
}

// R10: 2048 blocks x 128 thr (2 waves). Block owns 32 vectors; wave w scans
// candidates [w*256, w*256+256) with the EXACT R8 K-loop body (two-chain,
// ci-in-C, global L2-hot B). 8 blocks/CU -> 4 waves/SIMD. No atomics.
__global__ __launch_bounds__(128, 4) void vq_main(const float* __restrict__ vecs,
                                                  const _Float16* __restrict__ cbf16,
                                                  const float* __restrict__ c32,
                                                  const float* __restrict__ cnorm,
                                                  float* __restrict__ out,
                                                  float* __restrict__ partial) {
    __shared__ float cnL[512];
    __shared__ float bmL[2][32];
    __shared__ int   biL[2][32];
    __shared__ int   zL[32];

    const int tx   = threadIdx.x;
    const int lane = tx & 63;
    const int w    = tx >> 6;           // wave = candidate half
    const int col  = lane & 31;
    const int h    = lane >> 5;
    const int wvec = (int)blockIdx.x * 32;

    // cnorm -> LDS (4 loads/thread)
    #pragma unroll
    for (int i = 0; i < 4; ++i) cnL[tx + i * 128] = cnorm[tx + i * 128];

    // ---- A fragments (hi/lo f16) + vnorm (R4..R8-verified tree) ----
    half8 ahi[4], alo[4];
    float vnp = 0.0f;
    const float* arow = vecs + (size_t)(wvec + col) * KDIM + h * 8;
    #pragma unroll
    for (int q = 0; q < 4; ++q) {
        float4 x0 = *(const float4*)(arow + q * 16);
        float4 x1 = *(const float4*)(arow + q * 16 + 4);
        #define CVT(X, J) { float xx = (X); _Float16 hi5 = (_Float16)xx; \
                            float hf = (float)hi5; ahi[q][J] = hi5; \
                            alo[q][J] = (_Float16)(xx - hf); vnp += xx * xx; }
        CVT(x0.x, 0) CVT(x0.y, 1) CVT(x0.z, 2) CVT(x0.w, 3)
        CVT(x1.x, 4) CVT(x1.y, 5) CVT(x1.z, 6) CVT(x1.w, 7)
        #undef CVT
    }
    vnp += __shfl_xor(vnp, 32);

    __syncthreads();   // cnL visible

    // running argmax of m = -cn/2 + dot (== argmin dist; first-index ties)
    float bm[16];
    int   bi[16];
    #pragma unroll
    for (int r = 0; r < 16; ++r) { bm[r] = -3.4e38f; bi[r] = 0; }

    #pragma unroll
    for (int s8 = 0; s8 < 8; ++s8) {    // wave's 8 subs: j = w*8 + s8
        const int j = w * 8 + s8;
        const _Float16* bb = cbf16 + (size_t)j * 4096 + lane * 8;
        float ci = -0.5f * cnL[j * 32 + col];
        floatx16 a0, a1;
        #pragma unroll
        for (int r = 0; r < 16; ++r) { a0[r] = ci; a1[r] = 0.0f; }
        #pragma unroll
        for (int q = 0; q < 4; ++q) {
            half8 bh = *(const half8*)(bb + q * 512);          // global, L2-hot
            half8 bl = *(const half8*)(bb + 2048 + q * 512);
            a0 = __builtin_amdgcn_mfma_f32_32x32x16_f16(ahi[q], bh, a0, 0, 0, 0);
            a1 = __builtin_amdgcn_mfma_f32_32x32x16_f16(alo[q], bh, a1, 0, 0, 0);
            a1 = __builtin_amdgcn_mfma_f32_32x32x16_f16(ahi[q], bl, a1, 0, 0, 0);
        }
        int n = j * 32 + col;
        #pragma unroll
        for (int r = 0; r < 16; ++r) {
            float m = a0[r] + a1[r];
            if (m > bm[r]) { bm[r] = m; bi[r] = n; }   // strict >, increasing n
        }
    }

    // ---- cross-lane argmax per row within the wave ----
    #pragma unroll
    for (int r = 0; r < 16; ++r) {
        float v = bm[r]; int i = bi[r];
        #pragma unroll
        for (int off = 16; off > 0; off >>= 1) {
            float ov = __shfl_xor(v, off);
            int   oi = __shfl_xor(i, off);
            if (ov > v || (ov == v && oi < i)) { v = ov; i = oi; }
        }
        bm[r] = v; bi[r] = i;
    }

    // stash per-wave results (col==0 lanes cover all 32 rows via h)
    if (col == 0) {
        #pragma unroll
        for (int r = 0; r < 16; ++r) {
            int row = (r & 3) + 8 * (r >> 2) + 4 * h;   // C/D row map (verified)
            bmL[w][row] = bm[r];
            biL[w][row] = bi[r];
        }
    }
    __syncthreads();

    // ---- merge halves + outputs: wave 0, lanes 0..31 own row = lane ----
    float err = 0.0f;
    if (w == 0 && lane < 32) {
        int row = lane;
        float m0 = bmL[0][row], m1 = bmL[1][row];
        int   i0 = biL[0][row], i1 = biL[1][row];
        // half1 indices all > half0: take half1 only on strict >
        float mbest = m0; int ibest = i0;
        if (m1 > m0) { mbest = m1; ibest = i1; }
        err = fmaxf(vnp - 2.0f * mbest, 0.0f);   // lane==row holds vnp(row)
        int vid = wvec + row;
        out[Z_OFF + vid] = (float)ibest;          // coalesced across lanes
        out[E_OFF + vid] = err;
        zL[row] = ibest;
    }
    // block esum -> partial (lanes >=32 and wave 1 contribute 0)
    #pragma unroll
    for (int off = 32; off > 0; off >>= 1) err += __shfl_xor(err, off);
    if (tx == 0) partial[blockIdx.x] = err;

    __syncthreads();   // zL visible

    // ---- vecs_hat gather from c32 (L2-hot), coalesced float4 stores ----
    #pragma unroll
    for (int it = 0; it < 4; ++it) {
        int row = it * 8 + (tx >> 4);
        int c4  = tx & 15;
        int z   = zL[row];
        float4 val = *(const float4*)(c32 + (size_t)z * KDIM + c4 * 4);
        *(float4*)(out + (size_t)(wvec + row) * KDIM + c4 * 4) = val;
    }
}

// Final reduce: 2048 partials -> l_commit; also writes l_codebook = 0.
__global__ void vq_reduce(const float* __restrict__ partial,
                          float* __restrict__ out) {
    __shared__ float ws[4];
    int tx = threadIdx.x;
    float s = 0.0f;
    #pragma unroll
    for (int j = 0; j < 8; ++j) s += partial[tx + j * 256];
    #pragma unroll
    for (int off = 32; off > 0; off >>= 1) s += __shfl_down(s, off);
    if ((tx & 63) == 0) ws[tx >> 6] = s;
    __syncthreads();
    if (tx == 0) {
        float tot = ws[0] + ws[1] + ws[2] + ws[3];
        out[LCOMMIT_OFF] = tot * (1.0f / (float)NVEC);
        out[LCODE_OFF]   = 0.0f;
    }
}

extern "C" void kernel_launch(void* const* d_in, const int* in_sizes, int n_in,
                              void* d_out, int out_size, void* d_ws, size_t ws_size,
                              hipStream_t stream) {
    const float* vecs    = (const float*)d_in[0];  // [8,16,512,64]
    const float* c_sum   = (const float*)d_in[1];  // [512,64]
    const float* c_count = (const float*)d_in[2];  // [512]
    float* out = (float*)d_out;

    float*    c32     = (float*)d_ws;                      // [32768]
    float*    cnorm   = c32 + SDIM * KDIM;                 // [512]
    _Float16* cbf16   = (_Float16*)(cnorm + SDIM);         // [65536 halfs]
    float*    partial = (float*)(cbf16 + SDIM * KDIM * 2); // [2048]

    vq_prep<<<SDIM, KDIM, 0, stream>>>(c_sum, c_count, c32, cnorm, cbf16);
    vq_main<<<NVEC / 32, 128, 0, stream>>>(vecs, cbf16, c32, cnorm, out, partial);
    vq_reduce<<<1, 256, 0, stream>>>(partial, out);
}

// Round 11
// 101.086 us; speedup vs baseline: 5.0058x; 5.0058x over previous
//
#include <hip/hip_runtime.h>

// Problem constants
#define NVEC 65536      // B*R*C = 8*16*512
#define KDIM 64
#define SDIM 512

// Output layout (flat float32)
#define Z_OFF       4194304     // NVEC*KDIM
#define LCOMMIT_OFF 4259840
#define LCODE_OFF   4259841
#define E_OFF       4259842

typedef _Float16 half8    __attribute__((ext_vector_type(8)));
typedef float    floatx16 __attribute__((ext_vector_type(16)));

// ws layout (floats): c32 [32768], cnorm [512], cbf16 [65536 halfs], partial [2048]
// cbf16 chunk layout (R4-verified): half index
//   (s>>5)*4096 + p*2048 + q*512 + h*256 + (s&31)*8 + j
// -> per-lane read: bb = cbf16 + j*4096 + lane*8, bh at +q*512, bl at +2048+q*512.
//
// ALLOCATOR RULE (measured R2/R3/R9/R10): __launch_bounds__(_, N) caps arch
// VGPRs at 256/N. This kernel needs ~100 -> N must be 2. Occupancy comes from
// the grid (4096 waves = 4/SIMD), not the bound.

__global__ void vq_prep(const float* __restrict__ c_sum,
                        const float* __restrict__ c_count,
                        float* __restrict__ c32,
                        float* __restrict__ cnorm,
                        _Float16* __restrict__ cbf16) {
    int s = blockIdx.x;          // 0..511
    int k = threadIdx.x;         // 0..63
    float cnt = c_count[s];
    float inv = 1.0f / fmaxf(cnt, 0.01f);
    float x = c_sum[s * KDIM + k] * inv;
    c32[s * KDIM + k] = x;
    float sq = x * x;
    #pragma unroll
    for (int off = 32; off > 0; off >>= 1)
        sq += __shfl_down(sq, off);
    if (k == 0) cnorm[s] = sq;

    __shared__ _Float16 hb[64], lb[64];
    _Float16 hi = (_Float16)x;
    float hiF = (float)hi;
    _Float16 lo = (_Float16)(x - hiF);
    hb[k] = hi; lb[k] = lo;
    __syncthreads();
    if (k < 16) {
        int p  = k >> 3;
        int qh = k & 7;                       // q*2 + h
        int k0 = (qh >> 1) * 16 + (qh & 1) * 8;
        const _Float16* srcb = (p ? lb : hb) + k0;
        half8 v;
        #pragma unroll
        for (int j = 0; j < 8; ++j) v[j] = srcb[j];
        size_t chunk = ((size_t)(s >> 5) * 16 + p * 8 + qh) * 32 + (s & 31);
        *(half8*)(cbf16 + chunk * 8) = v;
    }
}

// R11 = R10 structure with the correct register bound. 2048 blocks x 128 thr
// (2 waves). Block owns 32 vectors; wave w scans candidates [w*256, w*256+256)
// with the EXACT R8 K-loop body. 4 waves/SIMD. No atomics.
__global__ __launch_bounds__(128, 2) void vq_main(const float* __restrict__ vecs,
                                                  const _Float16* __restrict__ cbf16,
                                                  const float* __restrict__ c32,
                                                  const float* __restrict__ cnorm,
                                                  float* __restrict__ out,
                                                  float* __restrict__ partial) {
    __shared__ float cnL[512];
    __shared__ float bmL[2][32];
    __shared__ int   biL[2][32];
    __shared__ int   zL[32];

    const int tx   = threadIdx.x;
    const int lane = tx & 63;
    const int w    = tx >> 6;           // wave = candidate half
    const int col  = lane & 31;
    const int h    = lane >> 5;
    const int wvec = (int)blockIdx.x * 32;

    // cnorm -> LDS (4 loads/thread)
    #pragma unroll
    for (int i = 0; i < 4; ++i) cnL[tx + i * 128] = cnorm[tx + i * 128];

    // ---- A fragments (hi/lo f16) + vnorm (R4..R8-verified tree) ----
    half8 ahi[4], alo[4];
    float vnp = 0.0f;
    const float* arow = vecs + (size_t)(wvec + col) * KDIM + h * 8;
    #pragma unroll
    for (int q = 0; q < 4; ++q) {
        float4 x0 = *(const float4*)(arow + q * 16);
        float4 x1 = *(const float4*)(arow + q * 16 + 4);
        #define CVT(X, J) { float xx = (X); _Float16 hi5 = (_Float16)xx; \
                            float hf = (float)hi5; ahi[q][J] = hi5; \
                            alo[q][J] = (_Float16)(xx - hf); vnp += xx * xx; }
        CVT(x0.x, 0) CVT(x0.y, 1) CVT(x0.z, 2) CVT(x0.w, 3)
        CVT(x1.x, 4) CVT(x1.y, 5) CVT(x1.z, 6) CVT(x1.w, 7)
        #undef CVT
    }
    vnp += __shfl_xor(vnp, 32);

    __syncthreads();   // cnL visible

    // running argmax of m = -cn/2 + dot (== argmin dist; first-index ties)
    float bm[16];
    int   bi[16];
    #pragma unroll
    for (int r = 0; r < 16; ++r) { bm[r] = -3.4e38f; bi[r] = 0; }

    #pragma unroll
    for (int s8 = 0; s8 < 8; ++s8) {    // wave's 8 subs: j = w*8 + s8
        const int j = w * 8 + s8;
        const _Float16* bb = cbf16 + (size_t)j * 4096 + lane * 8;
        float ci = -0.5f * cnL[j * 32 + col];
        floatx16 a0, a1;
        #pragma unroll
        for (int r = 0; r < 16; ++r) { a0[r] = ci; a1[r] = 0.0f; }
        #pragma unroll
        for (int q = 0; q < 4; ++q) {
            half8 bh = *(const half8*)(bb + q * 512);          // global, L2-hot
            half8 bl = *(const half8*)(bb + 2048 + q * 512);
            a0 = __builtin_amdgcn_mfma_f32_32x32x16_f16(ahi[q], bh, a0, 0, 0, 0);
            a1 = __builtin_amdgcn_mfma_f32_32x32x16_f16(alo[q], bh, a1, 0, 0, 0);
            a1 = __builtin_amdgcn_mfma_f32_32x32x16_f16(ahi[q], bl, a1, 0, 0, 0);
        }
        int n = j * 32 + col;
        #pragma unroll
        for (int r = 0; r < 16; ++r) {
            float m = a0[r] + a1[r];
            if (m > bm[r]) { bm[r] = m; bi[r] = n; }   // strict >, increasing n
        }
    }

    // ---- cross-lane argmax per row within the wave ----
    #pragma unroll
    for (int r = 0; r < 16; ++r) {
        float v = bm[r]; int i = bi[r];
        #pragma unroll
        for (int off = 16; off > 0; off >>= 1) {
            float ov = __shfl_xor(v, off);
            int   oi = __shfl_xor(i, off);
            if (ov > v || (ov == v && oi < i)) { v = ov; i = oi; }
        }
        bm[r] = v; bi[r] = i;
    }

    // stash per-wave results (col==0 lanes cover all 32 rows via h)
    if (col == 0) {
        #pragma unroll
        for (int r = 0; r < 16; ++r) {
            int row = (r & 3) + 8 * (r >> 2) + 4 * h;   // C/D row map (verified)
            bmL[w][row] = bm[r];
            biL[w][row] = bi[r];
        }
    }
    __syncthreads();

    // ---- merge halves + outputs: wave 0, lanes 0..31 own row = lane ----
    float err = 0.0f;
    if (w == 0 && lane < 32) {
        int row = lane;
        float m0 = bmL[0][row], m1 = bmL[1][row];
        int   i0 = biL[0][row], i1 = biL[1][row];
        // half1 indices all > half0: take half1 only on strict >
        float mbest = m0; int ibest = i0;
        if (m1 > m0) { mbest = m1; ibest = i1; }
        err = fmaxf(vnp - 2.0f * mbest, 0.0f);   // lane==row holds vnp(row)
        int vid = wvec + row;
        out[Z_OFF + vid] = (float)ibest;          // coalesced across lanes
        out[E_OFF + vid] = err;
        zL[row] = ibest;
    }
    // block esum -> partial (lanes >=32 and wave 1 contribute 0)
    #pragma unroll
    for (int off = 32; off > 0; off >>= 1) err += __shfl_xor(err, off);
    if (tx == 0) partial[blockIdx.x] = err;

    __syncthreads();   // zL visible

    // ---- vecs_hat gather from c32 (L2-hot), coalesced float4 stores ----
    #pragma unroll
    for (int it = 0; it < 4; ++it) {
        int row = it * 8 + (tx >> 4);
        int c4  = tx & 15;
        int z   = zL[row];
        float4 val = *(const float4*)(c32 + (size_t)z * KDIM + c4 * 4);
        *(float4*)(out + (size_t)(wvec + row) * KDIM + c4 * 4) = val;
    }
}

// Final reduce: 2048 partials -> l_commit; also writes l_codebook = 0.
__global__ void vq_reduce(const float* __restrict__ partial,
                          float* __restrict__ out) {
    __shared__ float ws[4];
    int tx = threadIdx.x;
    float s = 0.0f;
    #pragma unroll
    for (int j = 0; j < 8; ++j) s += partial[tx + j * 256];
    #pragma unroll
    for (int off = 32; off > 0; off >>= 1) s += __shfl_down(s, off);
    if ((tx & 63) == 0) ws[tx >> 6] = s;
    __syncthreads();
    if (tx == 0) {
        float tot = ws[0] + ws[1] + ws[2] + ws[3];
        out[LCOMMIT_OFF] = tot * (1.0f / (float)NVEC);
        out[LCODE_OFF]   = 0.0f;
    }
}

extern "C" void kernel_launch(void* const* d_in, const int* in_sizes, int n_in,
                              void* d_out, int out_size, void* d_ws, size_t ws_size,
                              hipStream_t stream) {
    const float* vecs    = (const float*)d_in[0];  // [8,16,512,64]
    const float* c_sum   = (const float*)d_in[1];  // [512,64]
    const float* c_count = (const float*)d_in[2];  // [512]
    float* out = (float*)d_out;

    float*    c32     = (float*)d_ws;                      // [32768]
    float*    cnorm   = c32 + SDIM * KDIM;                 // [512]
    _Float16* cbf16   = (_Float16*)(cnorm + SDIM);         // [65536 halfs]
    float*    partial = (float*)(cbf16 + SDIM * KDIM * 2); // [2048]

    vq_prep<<<SDIM, KDIM, 0, stream>>>(c_sum, c_count, c32, cnorm, cbf16);
    vq_main<<<NVEC / 32, 128, 0, stream>>>(vecs, cbf16, c32, cnorm, out, partial);
    vq_reduce<<<1, 256, 0, stream>>>(partial, out);
}